// Round 5
// baseline (142.316 us; speedup 1.0000x reference)
//
#include <hip/hip_runtime.h>
#include <hip/hip_bf16.h>

// Problem constants (EdgeAwareMultiHeadAttention)
constexpr int Bb   = 4;
constexpr int Nn   = 256;
constexpr int HID  = 256;
constexpr int Ee   = 64;
constexpr int Hh   = 4;
constexpr int OUTc = 128;   // HID/2
constexpr int Dd   = 32;    // OUT/H
constexpr int AGG  = 260;   // H*(2D+1)

typedef __attribute__((ext_vector_type(8))) short short8;
typedef __attribute__((ext_vector_type(4))) float floatx4;
typedef __attribute__((ext_vector_type(2))) float floatx2;

// HW packed f32x2 -> bf16x2 (v_cvt_pk_bf16_f32, RNE)
__device__ __forceinline__ unsigned pk2(float a, float b) {
    union { __hip_bfloat162 h; unsigned u; } cv;
    cv.h = __float22bfloat162_rn(float2{a, b});
    return cv.u;
}

__device__ __forceinline__ short8 pack8(floatx4 f0, floatx4 f1) {
    union { short8 s; unsigned u[4]; } r;
    r.u[0] = pk2(f0[0], f0[1]);
    r.u[1] = pk2(f0[2], f0[3]);
    r.u[2] = pk2(f1[0], f1[1]);
    r.u[3] = pk2(f1[2], f1[3]);
    return r.s;
}

// async global->LDS, 16B per lane. dst must be wave-uniform (HW adds lane*16).
__device__ __forceinline__ void gload16(const float* g, float* l) {
    __builtin_amdgcn_global_load_lds(
        (const __attribute__((address_space(1))) void*)g,
        (__attribute__((address_space(3))) void*)l, 16, 0, 0);
}

// ---------------- Single fused kernel: one block per bn ----------------
// R3 lesson: vmcnt is FIFO — compiler waits for its own (younger) prologue loads
// drained my (older) async h_e staging, serializing the prologue behind HBM.
// R4 order: (1) ALL compiler-visible prologue loads complete first, (2) sched_barrier(0)
// fence, (3) stage the block's ENTIRE 64KB h_e slice (16 x 1KB per wave, 4 tile
// buffers, no reuse), (4) main loop with counted vmcnt(12/8/4/0) — only tile 0's
// latency is ever exposed. LDS 74KB -> 2 blocks/CU (grid 1024 = 2 balanced rounds).
// R4 BUG FIXED HERE: epilogue per-wave regions now stride 4096 (= a wave's own
// staging area). R4 used stride 2048, so wave 1's pre-__syncthreads epilogue
// writes landed in wave 0's tiles-2/3 staging -> cross-wave race -> absmax fail.
__global__ __launch_bounds__(256, 2)
void eama_fused(const float* __restrict__ h_x, const float* __restrict__ h_e,
                const float* __restrict__ h_m,
                const float* __restrict__ W_Q, const float* __restrict__ W_K,
                const float* __restrict__ W_V, const float* __restrict__ W_R,
                float* __restrict__ out)
{
    // 64KB staging: [wave][tile][chunk j][lane][4 floats]. Dead after the main
    // loop; reused for the whole epilogue (per-wave regions + block scratch).
    __shared__ __align__(16) float sStage[4][4][4][64][4];
    __shared__ __align__(16) float sS[4][16][4];           // score patch (prologue: sU alias)
    __shared__ __align__(16) unsigned short sWin[512 * 8]; // 8KB W_V frag window
    __shared__ __align__(16) float sQp[256];               // q split-k partials / q

    const int tid  = threadIdx.x;
    const int lane = tid & 63;
    const int w    = tid >> 6;
    const int ncol = lane & 15;
    const int q8   = lane >> 4;
    const int bn   = blockIdx.x;

    // mask -> register predicate, pinned pre-fence so its wait can't land in the loop
    int moki = (h_m[bn] != 0.f) ? 1 : 0;
    asm volatile("" : "+v"(moki));

    // ---- W_V fragment pack via the 8KB window (2 chunks of 512 frags) ----
    // frag e = (ct*2+ks)*64 + lane_e: row = ct*16 + (e&15), k0 = ks*32 + ((e>>4)&3)*8.
    short8 bfV[8][2];
    #pragma unroll
    for (int c = 0; c < 2; ++c) {
        #pragma unroll
        for (int kk = 0; kk < 2; ++kk) {
            const int k  = kk * 256 + tid;                 // local 0..511, e = c*512+k
            const int ct = c * 4 + (k >> 7);
            const float* src = W_V + (size_t)(ct * 16 + (k & 15)) * Ee
                             + ((k >> 6) & 1) * 32 + ((k >> 4) & 3) * 8;
            *(short8*)&sWin[(size_t)k * 8] = pack8(*(const floatx4*)src,
                                                   *(const floatx4*)(src + 4));
        }
        __syncthreads();
        #pragma unroll
        for (int ct4 = 0; ct4 < 4; ++ct4)
            #pragma unroll
            for (int ks = 0; ks < 2; ++ks)
                bfV[c * 4 + ct4][ks] = *(const short8*)&sWin[((ct4 * 2 + ks) * 64 + lane) * 8];
        __syncthreads();
    }

    // ---- q[c] = W_Q[c,:] . h_x[bn,:]  (fp32, split-k over 2 halves) ----
    {
        const int c = tid & 127, half = tid >> 7;
        const float* wq = W_Q + (size_t)c * HID + half * 128;
        const float* xr = h_x + (size_t)bn * HID + half * 128;
        float acc = 0.f;
        #pragma unroll
        for (int i = 0; i < 32; ++i) {
            floatx4 a = *(const floatx4*)(wq + i * 4);
            floatx4 x = *(const floatx4*)(xr + i * 4);
            acc = fmaf(a[0], x[0], fmaf(a[1], x[1], fmaf(a[2], x[2], fmaf(a[3], x[3], acc))));
        }
        sQp[tid] = acc;
    }
    __syncthreads();
    if (tid < 128) sQp[tid] += sQp[tid + 128];
    __syncthreads();

    // ---- u[h][e] = (q[h*32..] . W_K[...,e]) * rsqrt(D), into sU (aliases sS) ----
    float* sU = &sS[0][0][0];
    {
        const int h = tid >> 6, e = tid & 63;
        float acc = 0.f;
        #pragma unroll
        for (int d = 0; d < 32; ++d)
            acc = fmaf(sQp[h * 32 + d], W_K[(size_t)(h * Dd + d) * Ee + e], acc);
        sU[h * 64 + e] = acc * 0.1767766952966369f;
    }
    __syncthreads();

    // pack bu0/bu1 B-fragments: row ncol (= head) valid for ncol<4, else zero
    short8 bu0 = {0, 0, 0, 0, 0, 0, 0, 0};
    short8 bu1 = {0, 0, 0, 0, 0, 0, 0, 0};
    if (ncol < Hh) {
        bu0 = pack8(*(const floatx4*)&sU[ncol * 64 + q8 * 8],
                    *(const floatx4*)&sU[ncol * 64 + q8 * 8 + 4]);
        bu1 = pack8(*(const floatx4*)&sU[ncol * 64 + 32 + q8 * 8],
                    *(const floatx4*)&sU[ncol * 64 + 32 + q8 * 8 + 4]);
    }
    __syncthreads();   // cross-wave sU reads done before main loop reuses sS

    // ---- fence: nothing (loads, waits, VALU) may cross; then stage everything ----
    __builtin_amdgcn_sched_barrier(0);
    {
        const float* heb = h_e + (size_t)bn * Nn * Ee;
        const float* arq = heb + (size_t)(w * 64 + ncol) * Ee + q8 * 8;
        #pragma unroll
        for (int it = 0; it < 4; ++it) {
            const float* ar = arq + (size_t)it * 16 * Ee;
            gload16(ar,      &sStage[w][it][0][0][0]);
            gload16(ar + 4,  &sStage[w][it][1][0][0]);
            gload16(ar + 32, &sStage[w][it][2][0][0]);
            gload16(ar + 36, &sStage[w][it][3][0][0]);
        }
    }
    __builtin_amdgcn_sched_barrier(0);

    float vs[8], vm[8], asumH = 0.f;
    #pragma unroll
    for (int ct = 0; ct < 8; ++ct) { vs[ct] = 0.f; vm[ct] = -3.402823466e38f; }

    #pragma unroll
    for (int it = 0; it < 4; ++it) {
        // counted wait: tiles it+1..3 (4 loads each) may stay in flight
        if (it == 0)      asm volatile("s_waitcnt vmcnt(12)" ::: "memory");
        else if (it == 1) asm volatile("s_waitcnt vmcnt(8)"  ::: "memory");
        else if (it == 2) asm volatile("s_waitcnt vmcnt(4)"  ::: "memory");
        else              asm volatile("s_waitcnt vmcnt(0)"  ::: "memory");

        floatx4 c0 = *(const floatx4*)&sStage[w][it][0][lane][0];
        floatx4 c1 = *(const floatx4*)&sStage[w][it][1][lane][0];
        floatx4 c2 = *(const floatx4*)&sStage[w][it][2][lane][0];
        floatx4 c3 = *(const floatx4*)&sStage[w][it][3][lane][0];
        short8 af0 = pack8(c0, c1);
        short8 af1 = pack8(c2, c3);

        floatx4 accV[8], accS = (floatx4){0, 0, 0, 0};
        #pragma unroll
        for (int ct = 0; ct < 8; ++ct) accV[ct] = (floatx4){0, 0, 0, 0};
        #pragma unroll
        for (int ct = 0; ct < 8; ++ct) {
            accV[ct] = __builtin_amdgcn_mfma_f32_16x16x32_bf16(af0, bfV[ct][0], accV[ct], 0, 0, 0);
            accV[ct] = __builtin_amdgcn_mfma_f32_16x16x32_bf16(af1, bfV[ct][1], accV[ct], 0, 0, 0);
        }
        accS = __builtin_amdgcn_mfma_f32_16x16x32_bf16(af0, bu0, accS, 0, 0, 0);
        accS = __builtin_amdgcn_mfma_f32_16x16x32_bf16(af1, bu1, accS, 0, 0, 0);

        // scores -> per-wave LDS patch (same-wave write/read; program order holds)
        if (ncol < Hh) {
            #pragma unroll
            for (int r = 0; r < 4; ++r)
                sS[w][q8 * 4 + r][ncol] = moki ? accS[r] : -1e30f;
        }
        __builtin_amdgcn_wave_barrier();

        #pragma unroll
        for (int r = 0; r < 4; ++r) {
            floatx4 sc = *(const floatx4*)&sS[w][q8 * 4 + r][0];
            float e0 = __expf(sc[0]), e1 = __expf(sc[1]);
            float e2 = __expf(sc[2]), e3 = __expf(sc[3]);
            float inv = 1.f / ((e0 + e1) + (e2 + e3));
            float a0 = e0 * inv, a1 = e1 * inv, a2 = e2 * inv, a3 = e3 * inv;
            asumH += (ncol & 2) ? ((ncol & 1) ? a3 : a2) : ((ncol & 1) ? a1 : a0);
            float p;
            p = a0 * accV[0][r]; vs[0] += p; vm[0] = fmaxf(vm[0], p);
            p = a0 * accV[1][r]; vs[1] += p; vm[1] = fmaxf(vm[1], p);
            p = a1 * accV[2][r]; vs[2] += p; vm[2] = fmaxf(vm[2], p);
            p = a1 * accV[3][r]; vs[3] += p; vm[3] = fmaxf(vm[3], p);
            p = a2 * accV[4][r]; vs[4] += p; vm[4] = fmaxf(vm[4], p);
            p = a2 * accV[5][r]; vs[5] += p; vm[5] = fmaxf(vm[5], p);
            p = a3 * accV[6][r]; vs[6] += p; vm[6] = fmaxf(vm[6], p);
            p = a3 * accV[7][r]; vs[7] += p; vm[7] = fmaxf(vm[7], p);
        }
        __builtin_amdgcn_wave_barrier();   // sS reused next tile
    }

    // q8-group reduction (once per wave)
    #pragma unroll
    for (int ct = 0; ct < 8; ++ct) {
        vs[ct] += __shfl_xor(vs[ct], 16, 64);
        vs[ct] += __shfl_xor(vs[ct], 32, 64);
        vm[ct] = fmaxf(vm[ct], __shfl_xor(vm[ct], 16, 64));
        vm[ct] = fmaxf(vm[ct], __shfl_xor(vm[ct], 32, 64));
    }
    asumH += __shfl_xor(asumH, 16, 64);
    asumH += __shfl_xor(asumH, 32, 64);

    // ---- epilogue in the dead sStage area ----
    // Per-wave region = the wave's OWN 4096-float staging area (stride 4096!):
    // wave w: sVS at [w*4096, +128), sVM at [w*4096+128, +128), sAS at [w*4096+256, +4).
    // Safe pre-sync: a wave only overwrites staging data it alone has already consumed.
    float* SB = &sStage[0][0][0][0][0];
    if (lane < 16) {
        #pragma unroll
        for (int ct = 0; ct < 8; ++ct) {
            SB[w * 4096 + ct * 16 + lane]       = vs[ct];
            SB[w * 4096 + 128 + ct * 16 + lane] = vm[ct];
        }
    }
    if (lane < Hh) SB[w * 4096 + 256 + lane] = asumH;
    __syncthreads();
    // block scratch below (offsets 512/768/1100 in wave 0's region) is written only
    // after the barrier and does not overlap any live per-wave [base, base+260) region.
    if (tid < Hh) {
        SB[512 + tid] = 1e-8f +
            (SB[0 * 4096 + 256 + tid] + SB[1 * 4096 + 256 + tid]) +
            (SB[2 * 4096 + 256 + tid] + SB[3 * 4096 + 256 + tid]);
    }
    __syncthreads();
    if (tid < OUTc) {
        float vsum = (SB[0 * 4096 + tid] + SB[1 * 4096 + tid]) +
                     (SB[2 * 4096 + tid] + SB[3 * 4096 + tid]);
        float vmax = fmaxf(fmaxf(SB[0 * 4096 + 128 + tid], SB[1 * 4096 + 128 + tid]),
                           fmaxf(SB[2 * 4096 + 128 + tid], SB[3 * 4096 + 128 + tid]));
        const int h = tid >> 5, d = tid & 31;
        SB[768 + h * 65 + d]      = vsum / SB[512 + h];
        SB[768 + h * 65 + 33 + d] = vmax;
        if (tid < Hh) SB[768 + tid * 65 + 32] = SB[512 + tid];
    }
    __syncthreads();
    // fused W_R GEMV reading W_R directly (row-contiguous per thread, L2-resident):
    // out[c] = sum_j M[j] * W_R[c*260 + j]; 2 j-halves of 130 across 256 threads
    {
        const int c = tid & 127, part = tid >> 7;
        const int j0 = part * 130;
        const float* wr = W_R + (size_t)c * AGG + j0;   // 8B-aligned (260, 130 even)
        const float* sM = SB + 768;
        float a0 = 0.f, a1 = 0.f, a2 = 0.f, a3 = 0.f;
        #pragma unroll 8
        for (int j = 0; j < 128; j += 4) {
            floatx2 A  = *(const floatx2*)(wr + j);
            floatx2 Bv = *(const floatx2*)(wr + j + 2);
            a0 = fmaf(sM[j0 + j],     A[0],  a0);
            a1 = fmaf(sM[j0 + j + 1], A[1],  a1);
            a2 = fmaf(sM[j0 + j + 2], Bv[0], a2);
            a3 = fmaf(sM[j0 + j + 3], Bv[1], a3);
        }
        floatx2 T = *(const floatx2*)(wr + 128);
        a0 = fmaf(sM[j0 + 128], T[0], a0);
        a1 = fmaf(sM[j0 + 129], T[1], a1);
        SB[1100 + part * 128 + c] = (a0 + a1) + (a2 + a3);
    }
    __syncthreads();
    if (tid < OUTc)
        out[(size_t)bn * OUTc + tid] = SB[1100 + tid] + SB[1100 + 128 + tid];
}

extern "C" void kernel_launch(void* const* d_in, const int* in_sizes, int n_in,
                              void* d_out, int out_size, void* d_ws, size_t ws_size,
                              hipStream_t stream) {
    const float* h_x = (const float*)d_in[0];
    const float* h_e = (const float*)d_in[1];
    const float* h_m = (const float*)d_in[2];
    const float* W_Q = (const float*)d_in[3];
    const float* W_K = (const float*)d_in[4];
    const float* W_V = (const float*)d_in[5];
    const float* W_R = (const float*)d_in[6];
    float* out = (float*)d_out;

    eama_fused<<<dim3(Bb * Nn), dim3(256), 0, stream>>>(
        h_x, h_e, h_m, W_Q, W_K, W_V, W_R, out);
}

// Round 6
// 125.815 us; speedup vs baseline: 1.1312x; 1.1312x over previous
//
#include <hip/hip_runtime.h>
#include <hip/hip_bf16.h>

// Problem constants (EdgeAwareMultiHeadAttention)
constexpr int Bb   = 4;
constexpr int Nn   = 256;
constexpr int HID  = 256;
constexpr int Ee   = 64;
constexpr int Hh   = 4;
constexpr int OUTc = 128;   // HID/2
constexpr int Dd   = 32;    // OUT/H
constexpr int AGG  = 260;   // H*(2D+1)
constexpr int REC  = 264;
constexpr int QA_LD = 264;  // bf16 row stride for Q-proj A tile

// ws layout (float offsets)
constexpr size_t WS_WRT   = 0;                                 // 260*128
constexpr size_t WS_FRAGV = WS_WRT + (size_t)AGG * OUTc;       // 1024 entries = 4096 floats
constexpr size_t WS_FRAGQ = WS_FRAGV + 4096;                   // (unused)
constexpr size_t WS_UFRAG = WS_FRAGQ + 16384;

typedef __attribute__((ext_vector_type(8))) short short8;
typedef __attribute__((ext_vector_type(4))) float floatx4;

// HW packed f32x2 -> bf16x2 (v_cvt_pk_bf16_f32, RNE)
__device__ __forceinline__ unsigned pk2(float a, float b) {
    union { __hip_bfloat162 h; unsigned u; } cv;
    cv.h = __float22bfloat162_rn(float2{a, b});
    return cv.u;
}

__device__ __forceinline__ short8 pack8(floatx4 f0, floatx4 f1) {
    union { short8 s; unsigned u[4]; } r;
    r.u[0] = pk2(f0[0], f0[1]);
    r.u[1] = pk2(f0[2], f0[3]);
    r.u[2] = pk2(f1[0], f1[1]);
    r.u[3] = pk2(f1[2], f1[3]);
    return r.s;
}

// async global->LDS, 16B per lane. dst must be wave-uniform (HW adds lane*16).
__device__ __forceinline__ void gload16(const float* g, float* l) {
    __builtin_amdgcn_global_load_lds(
        (const __attribute__((address_space(1))) void*)g,
        (__attribute__((address_space(3))) void*)l, 16, 0, 0);
}

// ---------------- K_prep: weight prepack (W_V frags, W_RT) + q/u projection ----------------
// blocks 0..3    : W_V fragment pack
// blocks 4..133  : W_RT transpose
// blocks 134..197: q = h_x@W_Q^T (MFMA) then u = q.W_K * rsqrt(D) * log2(e) -> ufrag
// (log2e folded here so the softmax in K_full can use a single v_exp_f32 per score)
__global__ __launch_bounds__(256)
void eama_prep(const float* __restrict__ W_Q, const float* __restrict__ W_V,
               const float* __restrict__ W_R, const float* __restrict__ h_x,
               const float* __restrict__ W_K,
               unsigned short* __restrict__ wfragV, float* __restrict__ W_RT,
               unsigned short* __restrict__ ufrag)
{
    __shared__ __align__(16) unsigned short sA[16 * QA_LD];
    __shared__ __align__(16) float sqL[16][132];
    __shared__ __align__(16) float sU2[16][256];

    const int tid = threadIdx.x;
    const int bid = blockIdx.x;

    if (bid < 4) {
        const int e    = bid * 256 + tid;          // 0..1023
        const int lane = e & 63;
        const int ks   = (e >> 6) & 1;
        const int ct   = e >> 7;                   // 0..7
        const int ncol = lane & 15, q8 = lane >> 4;
        const float* row = W_V + (ct * 16 + ncol) * Ee;
        const int k0 = ks * 32 + q8 * 8;
        floatx4 f0 = *(const floatx4*)(row + k0);
        floatx4 f1 = *(const floatx4*)(row + k0 + 4);
        *(short8*)(wfragV + (size_t)e * 8) = pack8(f0, f1);
        return;
    }
    if (bid < 134) {
        const int i = (bid - 4) * 256 + tid;       // 0..33279
        if (i < AGG * OUTc) {
            const int c = i & 127, j = i >> 7;
            W_RT[j * OUTc + c] = W_R[c * AGG + j];
        }
        return;
    }

    // ---- q = h_x @ W_Q^T (MFMA), then u[h,e] = q.W_K * rsqrt(D)*log2e -> ufrag ----
    const int b0   = (bid - 134) * 16;
    const int lane = tid & 63;
    const int wv   = tid >> 6;
    const int ncol = lane & 15, q8 = lane >> 4;

    // gather W_Q fragments directly (L2-resident, 128KB shared by 64 blocks)
    short8 bq[2][8];
    #pragma unroll
    for (int ct = 0; ct < 2; ++ct)
        #pragma unroll
        for (int ks = 0; ks < 8; ++ks) {
            const float* row = W_Q + (size_t)(wv * 32 + ct * 16 + ncol) * HID + ks * 32 + q8 * 8;
            bq[ct][ks] = pack8(*(const floatx4*)row, *(const floatx4*)(row + 4));
        }
    #pragma unroll
    for (int i = 0; i < 2; ++i) {
        const int idx = tid + i * 256;
        const int r = idx >> 5, blk = idx & 31;
        const float* src = h_x + (size_t)(b0 + r) * HID + blk * 8;
        floatx4 f0 = *(const floatx4*)(src);
        floatx4 f1 = *(const floatx4*)(src + 4);
        *(short8*)&sA[r * QA_LD + blk * 8] = pack8(f0, f1);
    }
    __syncthreads();
    floatx4 acc[2] = {(floatx4){0,0,0,0}, (floatx4){0,0,0,0}};
    #pragma unroll
    for (int ks = 0; ks < 8; ++ks) {
        short8 a = *(const short8*)&sA[ncol * QA_LD + ks * 32 + q8 * 8];
        acc[0] = __builtin_amdgcn_mfma_f32_16x16x32_bf16(a, bq[0][ks], acc[0], 0, 0, 0);
        acc[1] = __builtin_amdgcn_mfma_f32_16x16x32_bf16(a, bq[1][ks], acc[1], 0, 0, 0);
    }
    #pragma unroll
    for (int ct = 0; ct < 2; ++ct)
        #pragma unroll
        for (int rr = 0; rr < 4; ++rr)
            sqL[q8 * 4 + rr][wv * 32 + ct * 16 + ncol] = acc[ct][rr];
    __syncthreads();

    {
        const int h = wv, e = lane;
        float a16[16];
        #pragma unroll
        for (int i = 0; i < 16; ++i) a16[i] = 0.f;
        #pragma unroll
        for (int d4 = 0; d4 < 8; ++d4) {
            float wk0 = W_K[(h * Dd + d4 * 4 + 0) * Ee + e];
            float wk1 = W_K[(h * Dd + d4 * 4 + 1) * Ee + e];
            float wk2 = W_K[(h * Dd + d4 * 4 + 2) * Ee + e];
            float wk3 = W_K[(h * Dd + d4 * 4 + 3) * Ee + e];
            #pragma unroll
            for (int b16 = 0; b16 < 16; ++b16) {
                floatx4 qv = *(const floatx4*)&sqL[b16][h * Dd + d4 * 4];
                a16[b16] += (qv[0] * wk0 + qv[1] * wk1) + (qv[2] * wk2 + qv[3] * wk3);
            }
        }
        // rsqrt(D) * log2(e): scores leave MFMA already in log2 domain
        #pragma unroll
        for (int b16 = 0; b16 < 16; ++b16)
            sU2[b16][h * 64 + e] = a16[b16] * (0.1767766952966369f * 1.4426950408889634f);
    }
    __syncthreads();

    #pragma unroll
    for (int k = 0; k < 8; ++k) {
        const int ei   = tid + k * 256;
        const int b16  = ei >> 7;
        const int rest = ei & 127;
        const int ks   = rest >> 6;
        const int l    = rest & 63;
        const int nc   = l & 15, qq = l >> 4;
        short8 v = {0, 0, 0, 0, 0, 0, 0, 0};
        if (nc < Hh) {
            floatx4 f0 = *(const floatx4*)&sU2[b16][nc * 64 + ks * 32 + qq * 8];
            floatx4 f1 = *(const floatx4*)&sU2[b16][nc * 64 + ks * 32 + qq * 8 + 4];
            v = pack8(f0, f1);
        }
        *(short8*)(ufrag + ((size_t)((b0 + b16) * 2 + ks) * 64 + l) * 8) = v;
    }
}

// ---------------- K_full: one block per bn — V-proj + head-softmax + agg + W_R GEMV ----------------
// EXACT R2 structure (measured <=41us, 4 blk/CU) with three serial-chain cuts:
//  (1) exp2-domain softmax (log2e pre-folded into u) -> one v_exp_f32 per score
//  (2) v_rcp_f32 for the softmax normalizer (was ~10-instr full-precision divide)
//  (3) s_setprio(1) around the MFMA cluster (independent attn-like waves: +4-7% regime)
__global__ __launch_bounds__(256, 2)
void eama_full(const float* __restrict__ h_e, const float* __restrict__ h_m,
               const unsigned short* __restrict__ wfragV,
               const unsigned short* __restrict__ ufrag,
               const float* __restrict__ W_RT, float* __restrict__ out)
{
    // 32KB staging: [wave][buf][chunk j][lane][4 floats]. Dead after the main loop;
    // its space is reused for the epilogue sM / sAcc (first write is after __syncthreads()).
    __shared__ __align__(16) float sStage[4][2][4][64][4];
    __shared__ __align__(16) float sS[4][16][4];   // per-wave score patch
    __shared__ float sVS[4][OUTc];
    __shared__ float sVM[4][OUTc];
    __shared__ float sAS[4][Hh];
    __shared__ float sAsum[Hh];

    float* sM = &sStage[0][0][0][0][0];                    // REC floats (alias, post-loop)
    float (*sAcc)[OUTc] = (float (*)[OUTc])(sM + 384);     // 2*128 floats (alias, post-loop)

    const int tid  = threadIdx.x;
    const int lane = tid & 63;
    const int w    = tid >> 6;
    const int ncol = lane & 15;
    const int q8   = lane >> 4;
    const int bn   = blockIdx.x;
    const float maskv = h_m[bn];

    // B fragments once per wave (coalesced 16B/lane, L2-resident)
    short8 bfV[8][2];
    #pragma unroll
    for (int ct = 0; ct < 8; ++ct)
        #pragma unroll
        for (int ks = 0; ks < 2; ++ks)
            bfV[ct][ks] = *(const short8*)(wfragV + ((size_t)(ct * 2 + ks) * 64 + lane) * 8);
    short8 bu0 = *(const short8*)(ufrag + ((size_t)(bn * 2 + 0) * 64 + lane) * 8);
    short8 bu1 = *(const short8*)(ufrag + ((size_t)(bn * 2 + 1) * 64 + lane) * 8);
    asm volatile("" ::: "memory");   // pin B-frag loads before the staging stream (vmcnt order)

    const float* heb = h_e + (size_t)bn * Nn * Ee;
    // per-lane global row base (row = w*64 + it*16 + ncol), q8 selects the 32B column slot
    const float* arq = heb + (size_t)(w * 64 + ncol) * Ee + q8 * 8;

    // tile it -> buf: 4 async 1KB copies; LDS dst is wave-uniform, HW adds lane*16
    #define STAGE(it_, buf_) do { \
        const float* ar_ = arq + (size_t)(it_) * 16 * Ee; \
        gload16(ar_,      &sStage[w][buf_][0][0][0]); \
        gload16(ar_ + 4,  &sStage[w][buf_][1][0][0]); \
        gload16(ar_ + 32, &sStage[w][buf_][2][0][0]); \
        gload16(ar_ + 36, &sStage[w][buf_][3][0][0]); \
    } while (0)

    STAGE(0, 0);
    STAGE(1, 1);

    float vs[8], vm[8], asumH = 0.f;
    #pragma unroll
    for (int ct = 0; ct < 8; ++ct) { vs[ct] = 0.f; vm[ct] = -3.402823466e38f; }

    #pragma unroll
    for (int it = 0; it < 4; ++it) {
        const int buf = it & 1;
        // counted wait: 4 younger staging loads (next tile) may stay in flight
        if (it < 3) asm volatile("s_waitcnt vmcnt(4)" ::: "memory");
        else        asm volatile("s_waitcnt vmcnt(0)" ::: "memory");

        floatx4 c0 = *(const floatx4*)&sStage[w][buf][0][lane][0];
        floatx4 c1 = *(const floatx4*)&sStage[w][buf][1][lane][0];
        floatx4 c2 = *(const floatx4*)&sStage[w][buf][2][lane][0];
        floatx4 c3 = *(const floatx4*)&sStage[w][buf][3][lane][0];
        short8 af0 = pack8(c0, c1);
        short8 af1 = pack8(c2, c3);
        if (it < 2) {
            // ds_reads of this buf must retire before the async overwrite can land
            asm volatile("s_waitcnt lgkmcnt(0)" ::: "memory");
            STAGE(it + 2, buf);
        }

        floatx4 accV[8], accS = (floatx4){0, 0, 0, 0};
        #pragma unroll
        for (int ct = 0; ct < 8; ++ct) accV[ct] = (floatx4){0, 0, 0, 0};
        __builtin_amdgcn_s_setprio(1);
        #pragma unroll
        for (int ct = 0; ct < 8; ++ct) {
            accV[ct] = __builtin_amdgcn_mfma_f32_16x16x32_bf16(af0, bfV[ct][0], accV[ct], 0, 0, 0);
            accV[ct] = __builtin_amdgcn_mfma_f32_16x16x32_bf16(af1, bfV[ct][1], accV[ct], 0, 0, 0);
        }
        accS = __builtin_amdgcn_mfma_f32_16x16x32_bf16(af0, bu0, accS, 0, 0, 0);
        accS = __builtin_amdgcn_mfma_f32_16x16x32_bf16(af1, bu1, accS, 0, 0, 0);
        __builtin_amdgcn_s_setprio(0);

        // scores -> per-wave LDS patch (same-wave write/read; program order holds)
        if (ncol < Hh) {
            #pragma unroll
            for (int r = 0; r < 4; ++r)
                sS[w][q8 * 4 + r][ncol] = (maskv != 0.f) ? accS[r] : -1e30f;
        }
        __builtin_amdgcn_wave_barrier();

        #pragma unroll
        for (int r = 0; r < 4; ++r) {
            floatx4 sc = *(const floatx4*)&sS[w][q8 * 4 + r][0];
            // scores are in log2 domain (log2e folded into u at prep): one v_exp_f32 each
            float e0 = __builtin_amdgcn_exp2f(sc[0]), e1 = __builtin_amdgcn_exp2f(sc[1]);
            float e2 = __builtin_amdgcn_exp2f(sc[2]), e3 = __builtin_amdgcn_exp2f(sc[3]);
            float inv = __builtin_amdgcn_rcpf((e0 + e1) + (e2 + e3));   // v_rcp_f32, ~1ulp
            float a0 = e0 * inv, a1 = e1 * inv, a2 = e2 * inv, a3 = e3 * inv;
            asumH += (ncol & 2) ? ((ncol & 1) ? a3 : a2) : ((ncol & 1) ? a1 : a0);
            float p;
            p = a0 * accV[0][r]; vs[0] += p; vm[0] = fmaxf(vm[0], p);
            p = a0 * accV[1][r]; vs[1] += p; vm[1] = fmaxf(vm[1], p);
            p = a1 * accV[2][r]; vs[2] += p; vm[2] = fmaxf(vm[2], p);
            p = a1 * accV[3][r]; vs[3] += p; vm[3] = fmaxf(vm[3], p);
            p = a2 * accV[4][r]; vs[4] += p; vm[4] = fmaxf(vm[4], p);
            p = a2 * accV[5][r]; vs[5] += p; vm[5] = fmaxf(vm[5], p);
            p = a3 * accV[6][r]; vs[6] += p; vm[6] = fmaxf(vm[6], p);
            p = a3 * accV[7][r]; vs[7] += p; vm[7] = fmaxf(vm[7], p);
        }
        __builtin_amdgcn_wave_barrier();   // sS reused next tile
    }
    #undef STAGE

    // q8-group reduction (once per wave)
    #pragma unroll
    for (int ct = 0; ct < 8; ++ct) {
        vs[ct] += __shfl_xor(vs[ct], 16, 64);
        vs[ct] += __shfl_xor(vs[ct], 32, 64);
        vm[ct] = fmaxf(vm[ct], __shfl_xor(vm[ct], 16, 64));
        vm[ct] = fmaxf(vm[ct], __shfl_xor(vm[ct], 32, 64));
    }
    asumH += __shfl_xor(asumH, 16, 64);
    asumH += __shfl_xor(asumH, 32, 64);

    if (lane < 16) {
        #pragma unroll
        for (int ct = 0; ct < 8; ++ct) {
            sVS[w][ct * 16 + lane] = vs[ct];
            sVM[w][ct * 16 + lane] = vm[ct];
        }
    }
    if (lane < Hh) sAS[w][lane] = asumH;   // lane = ncol = head
    __syncthreads();                       // all waves done -> sStage now dead, reusable
    if (tid < Hh) {
        sAsum[tid] = 1e-8f +
            (sAS[0][tid] + sAS[1][tid]) + (sAS[2][tid] + sAS[3][tid]);
    }
    __syncthreads();
    if (tid < OUTc) {
        float vsum = (sVS[0][tid] + sVS[1][tid]) + (sVS[2][tid] + sVS[3][tid]);
        float vmax = fmaxf(fmaxf(sVM[0][tid], sVM[1][tid]), fmaxf(sVM[2][tid], sVM[3][tid]));
        const int h = tid >> 5, d = tid & 31;
        sM[h * 65 + d]      = vsum / sAsum[h];
        sM[h * 65 + 33 + d] = vmax;
        if (tid < Hh) sM[tid * 65 + 32] = sAsum[tid];
    }
    __syncthreads();
    // fused W_R GEMV on transposed W_RT (coalesced: consecutive c = consecutive addr)
    {
        const int c = tid & 127, part = tid >> 7;
        const int j0 = part * 130;
        float a0 = 0.f, a1 = 0.f, a2 = 0.f, a3 = 0.f;
        #pragma unroll 4
        for (int j = j0; j < j0 + 128; j += 4) {
            a0 = fmaf(sM[j],     W_RT[(j)     * OUTc + c], a0);
            a1 = fmaf(sM[j + 1], W_RT[(j + 1) * OUTc + c], a1);
            a2 = fmaf(sM[j + 2], W_RT[(j + 2) * OUTc + c], a2);
            a3 = fmaf(sM[j + 3], W_RT[(j + 3) * OUTc + c], a3);
        }
        a0 = fmaf(sM[j0 + 128], W_RT[(j0 + 128) * OUTc + c], a0);
        a1 = fmaf(sM[j0 + 129], W_RT[(j0 + 129) * OUTc + c], a1);
        sAcc[part][c] = (a0 + a1) + (a2 + a3);
    }
    __syncthreads();
    if (tid < OUTc)
        out[bn * OUTc + tid] = sAcc[0][tid] + sAcc[1][tid];
}

extern "C" void kernel_launch(void* const* d_in, const int* in_sizes, int n_in,
                              void* d_out, int out_size, void* d_ws, size_t ws_size,
                              hipStream_t stream) {
    const float* h_x = (const float*)d_in[0];
    const float* h_e = (const float*)d_in[1];
    const float* h_m = (const float*)d_in[2];
    const float* W_Q = (const float*)d_in[3];
    const float* W_K = (const float*)d_in[4];
    const float* W_V = (const float*)d_in[5];
    const float* W_R = (const float*)d_in[6];
    float* out = (float*)d_out;

    float* ws            = (float*)d_ws;
    float* W_RT          = ws + WS_WRT;
    unsigned short* wfV  = (unsigned short*)(ws + WS_FRAGV);
    unsigned short* ufr  = (unsigned short*)(ws + WS_UFRAG);

    eama_prep<<<dim3(198), dim3(256), 0, stream>>>(W_Q, W_V, W_R, h_x, W_K, wfV, W_RT, ufr);
    eama_full<<<dim3(Bb * Nn), dim3(256), 0, stream>>>(h_e, h_m, wfV, ufr, W_RT, out);
}

// Round 7
// 124.533 us; speedup vs baseline: 1.1428x; 1.0103x over previous
//
#include <hip/hip_runtime.h>
#include <hip/hip_bf16.h>

// Problem constants (EdgeAwareMultiHeadAttention)
constexpr int Bb   = 4;
constexpr int Nn   = 256;
constexpr int HID  = 256;
constexpr int Ee   = 64;
constexpr int Hh   = 4;
constexpr int OUTc = 128;   // HID/2
constexpr int Dd   = 32;    // OUT/H
constexpr int AGG  = 260;   // H*(2D+1)
constexpr int REC  = 264;
constexpr int QA_LD = 264;  // bf16 row stride for Q-proj A tile

// ws layout (float offsets)
constexpr size_t WS_WRT   = 0;                                 // 260*128
constexpr size_t WS_FRAGV = WS_WRT + (size_t)AGG * OUTc;       // 1024 entries = 4096 floats
constexpr size_t WS_FRAGQ = WS_FRAGV + 4096;                   // (unused)
constexpr size_t WS_UFRAG = WS_FRAGQ + 16384;

typedef __attribute__((ext_vector_type(8))) short short8;
typedef __attribute__((ext_vector_type(4))) float floatx4;

// HW packed f32x2 -> bf16x2 (v_cvt_pk_bf16_f32, RNE)
__device__ __forceinline__ unsigned pk2(float a, float b) {
    union { __hip_bfloat162 h; unsigned u; } cv;
    cv.h = __float22bfloat162_rn(float2{a, b});
    return cv.u;
}

__device__ __forceinline__ short8 pack8(floatx4 f0, floatx4 f1) {
    union { short8 s; unsigned u[4]; } r;
    r.u[0] = pk2(f0[0], f0[1]);
    r.u[1] = pk2(f0[2], f0[3]);
    r.u[2] = pk2(f1[0], f1[1]);
    r.u[3] = pk2(f1[2], f1[3]);
    return r.s;
}

// async global->LDS, 16B per lane. dst must be wave-uniform (HW adds lane*16).
__device__ __forceinline__ void gload16(const float* g, float* l) {
    __builtin_amdgcn_global_load_lds(
        (const __attribute__((address_space(1))) void*)g,
        (__attribute__((address_space(3))) void*)l, 16, 0, 0);
}

// ---------------- K_prep: weight prepack (W_V frags, W_RT) + q/u projection ----------------
// blocks 0..3    : W_V fragment pack
// blocks 4..133  : W_RT transpose
// blocks 134..197: q = h_x@W_Q^T (MFMA) then u = q.W_K * rsqrt(D) * log2(e) -> ufrag
__global__ __launch_bounds__(256)
void eama_prep(const float* __restrict__ W_Q, const float* __restrict__ W_V,
               const float* __restrict__ W_R, const float* __restrict__ h_x,
               const float* __restrict__ W_K,
               unsigned short* __restrict__ wfragV, float* __restrict__ W_RT,
               unsigned short* __restrict__ ufrag)
{
    __shared__ __align__(16) unsigned short sA[16 * QA_LD];
    __shared__ __align__(16) float sqL[16][132];
    __shared__ __align__(16) float sU2[16][256];

    const int tid = threadIdx.x;
    const int bid = blockIdx.x;

    if (bid < 4) {
        const int e    = bid * 256 + tid;          // 0..1023
        const int lane = e & 63;
        const int ks   = (e >> 6) & 1;
        const int ct   = e >> 7;                   // 0..7
        const int ncol = lane & 15, q8 = lane >> 4;
        const float* row = W_V + (ct * 16 + ncol) * Ee;
        const int k0 = ks * 32 + q8 * 8;
        floatx4 f0 = *(const floatx4*)(row + k0);
        floatx4 f1 = *(const floatx4*)(row + k0 + 4);
        *(short8*)(wfragV + (size_t)e * 8) = pack8(f0, f1);
        return;
    }
    if (bid < 134) {
        const int i = (bid - 4) * 256 + tid;       // 0..33279
        if (i < AGG * OUTc) {
            const int c = i & 127, j = i >> 7;
            W_RT[j * OUTc + c] = W_R[c * AGG + j];
        }
        return;
    }

    // ---- q = h_x @ W_Q^T (MFMA), then u[h,e] = q.W_K * rsqrt(D)*log2e -> ufrag ----
    const int b0   = (bid - 134) * 16;
    const int lane = tid & 63;
    const int wv   = tid >> 6;
    const int ncol = lane & 15, q8 = lane >> 4;

    // gather W_Q fragments directly (L2-resident, 128KB shared by 64 blocks)
    short8 bq[2][8];
    #pragma unroll
    for (int ct = 0; ct < 2; ++ct)
        #pragma unroll
        for (int ks = 0; ks < 8; ++ks) {
            const float* row = W_Q + (size_t)(wv * 32 + ct * 16 + ncol) * HID + ks * 32 + q8 * 8;
            bq[ct][ks] = pack8(*(const floatx4*)row, *(const floatx4*)(row + 4));
        }
    #pragma unroll
    for (int i = 0; i < 2; ++i) {
        const int idx = tid + i * 256;
        const int r = idx >> 5, blk = idx & 31;
        const float* src = h_x + (size_t)(b0 + r) * HID + blk * 8;
        floatx4 f0 = *(const floatx4*)(src);
        floatx4 f1 = *(const floatx4*)(src + 4);
        *(short8*)&sA[r * QA_LD + blk * 8] = pack8(f0, f1);
    }
    __syncthreads();
    floatx4 acc[2] = {(floatx4){0,0,0,0}, (floatx4){0,0,0,0}};
    #pragma unroll
    for (int ks = 0; ks < 8; ++ks) {
        short8 a = *(const short8*)&sA[ncol * QA_LD + ks * 32 + q8 * 8];
        acc[0] = __builtin_amdgcn_mfma_f32_16x16x32_bf16(a, bq[0][ks], acc[0], 0, 0, 0);
        acc[1] = __builtin_amdgcn_mfma_f32_16x16x32_bf16(a, bq[1][ks], acc[1], 0, 0, 0);
    }
    #pragma unroll
    for (int ct = 0; ct < 2; ++ct)
        #pragma unroll
        for (int rr = 0; rr < 4; ++rr)
            sqL[q8 * 4 + rr][wv * 32 + ct * 16 + ncol] = acc[ct][rr];
    __syncthreads();

    {
        const int h = wv, e = lane;
        float a16[16];
        #pragma unroll
        for (int i = 0; i < 16; ++i) a16[i] = 0.f;
        #pragma unroll
        for (int d4 = 0; d4 < 8; ++d4) {
            float wk0 = W_K[(h * Dd + d4 * 4 + 0) * Ee + e];
            float wk1 = W_K[(h * Dd + d4 * 4 + 1) * Ee + e];
            float wk2 = W_K[(h * Dd + d4 * 4 + 2) * Ee + e];
            float wk3 = W_K[(h * Dd + d4 * 4 + 3) * Ee + e];
            #pragma unroll
            for (int b16 = 0; b16 < 16; ++b16) {
                floatx4 qv = *(const floatx4*)&sqL[b16][h * Dd + d4 * 4];
                a16[b16] += (qv[0] * wk0 + qv[1] * wk1) + (qv[2] * wk2 + qv[3] * wk3);
            }
        }
        // rsqrt(D) * log2(e): scores leave MFMA already in log2 domain
        #pragma unroll
        for (int b16 = 0; b16 < 16; ++b16)
            sU2[b16][h * 64 + e] = a16[b16] * (0.1767766952966369f * 1.4426950408889634f);
    }
    __syncthreads();

    #pragma unroll
    for (int k = 0; k < 8; ++k) {
        const int ei   = tid + k * 256;
        const int b16  = ei >> 7;
        const int rest = ei & 127;
        const int ks   = rest >> 6;
        const int l    = rest & 63;
        const int nc   = l & 15, qq = l >> 4;
        short8 v = {0, 0, 0, 0, 0, 0, 0, 0};
        if (nc < Hh) {
            floatx4 f0 = *(const floatx4*)&sU2[b16][nc * 64 + ks * 32 + qq * 8];
            floatx4 f1 = *(const floatx4*)&sU2[b16][nc * 64 + ks * 32 + qq * 8 + 4];
            v = pack8(f0, f1);
        }
        *(short8*)(ufrag + ((size_t)((b0 + b16) * 2 + ks) * 64 + l) * 8) = v;
    }
}

// ---------------- K_full: one block per bn — V-proj + head-softmax + agg + W_R GEMV ----------------
// R6 structure with ONE change: COALESCED staging. Old STAGE instructions were
// 64x16B scatters over 16 rows (row stride 256B) -> ~64 VMEM requests/instr;
// kernel was request-rate bound (R5 evidence: L3-resident run same 55us).
// New: chunk j = 4 CONSECUTIVE rows = contiguous 1KB per gload16 (8 lines/instr).
// LDS slot permutation: piece (rl,t) -> slot rl*16 + ((t+5*rl)&15); staging lane l
// fetches (rl=l>>4, t=((l&15)-5*rl)&15) so linear dst reproduces it; consumer reads
// slot(rl,t) -> 8 bank-groups touched per read (odd-multiplier rotation), ~optimal.
// A-row ncol still = global row it*16+ncol (identity): downstream math unchanged.
__global__ __launch_bounds__(256, 2)
void eama_full(const float* __restrict__ h_e, const float* __restrict__ h_m,
               const unsigned short* __restrict__ wfragV,
               const unsigned short* __restrict__ ufrag,
               const float* __restrict__ W_RT, float* __restrict__ out)
{
    // 32KB staging: [wave][buf][chunk j][slot][4 floats]. Dead after the main loop;
    // its space is reused for the epilogue sM / sAcc (first write is after __syncthreads()).
    __shared__ __align__(16) float sStage[4][2][4][64][4];
    __shared__ __align__(16) float sS[4][16][4];   // per-wave score patch
    __shared__ float sVS[4][OUTc];
    __shared__ float sVM[4][OUTc];
    __shared__ float sAS[4][Hh];
    __shared__ float sAsum[Hh];

    float* sM = &sStage[0][0][0][0][0];                    // REC floats (alias, post-loop)
    float (*sAcc)[OUTc] = (float (*)[OUTc])(sM + 384);     // 2*128 floats (alias, post-loop)

    const int tid  = threadIdx.x;
    const int lane = tid & 63;
    const int w    = tid >> 6;
    const int ncol = lane & 15;
    const int q8   = lane >> 4;
    const int bn   = blockIdx.x;
    const float maskv = h_m[bn];

    // B fragments once per wave (coalesced 16B/lane, L2-resident)
    short8 bfV[8][2];
    #pragma unroll
    for (int ct = 0; ct < 8; ++ct)
        #pragma unroll
        for (int ks = 0; ks < 2; ++ks)
            bfV[ct][ks] = *(const short8*)(wfragV + ((size_t)(ct * 2 + ks) * 64 + lane) * 8);
    short8 bu0 = *(const short8*)(ufrag + ((size_t)(bn * 2 + 0) * 64 + lane) * 8);
    short8 bu1 = *(const short8*)(ufrag + ((size_t)(bn * 2 + 1) * 64 + lane) * 8);
    asm volatile("" ::: "memory");   // pin B-frag loads before the staging stream (vmcnt order)

    const float* heb = h_e + (size_t)bn * Nn * Ee;

    // staging per-lane source offset: lane l fetches piece (rl = l>>4, t = ((l&15)-5*rl)&15)
    // of its chunk -> linear LDS dst slot l holds piece at slot rl*16 + ((t+5*rl)&15).
    const int rl_s = lane >> 4;
    const int t_s  = ((lane & 15) - 5 * rl_s) & 15;
    const int soff = rl_s * 64 + t_s * 4;   // float offset within the chunk's 1KB

    // consumer word offsets (within a chunk) for row ncol: chunk jc = ncol>>2, rl = ncol&3
    const int rl_c = ncol & 3;
    const int jc   = ncol >> 2;
    const int o0 = (rl_c * 16 + (((q8 * 2)     + 5 * rl_c) & 15)) * 4;
    const int o1 = (rl_c * 16 + (((q8 * 2 + 1) + 5 * rl_c) & 15)) * 4;
    const int o2 = (rl_c * 16 + (((q8 * 2 + 8) + 5 * rl_c) & 15)) * 4;
    const int o3 = (rl_c * 16 + (((q8 * 2 + 9) + 5 * rl_c) & 15)) * 4;

    // tile it -> buf: 4 async copies, each CONTIGUOUS 1KB (4 rows)
    #define STAGE(it_, buf_) do { \
        const float* ar_ = heb + (size_t)(w * 64 + (it_) * 16) * Ee + soff; \
        gload16(ar_,       &sStage[w][buf_][0][0][0]); \
        gload16(ar_ + 256, &sStage[w][buf_][1][0][0]); \
        gload16(ar_ + 512, &sStage[w][buf_][2][0][0]); \
        gload16(ar_ + 768, &sStage[w][buf_][3][0][0]); \
    } while (0)

    STAGE(0, 0);
    STAGE(1, 1);

    float vs[8], vm[8], asumH = 0.f;
    #pragma unroll
    for (int ct = 0; ct < 8; ++ct) { vs[ct] = 0.f; vm[ct] = -3.402823466e38f; }

    #pragma unroll
    for (int it = 0; it < 4; ++it) {
        const int buf = it & 1;
        // counted wait: 4 younger staging loads (next tile) may stay in flight
        if (it < 3) asm volatile("s_waitcnt vmcnt(4)" ::: "memory");
        else        asm volatile("s_waitcnt vmcnt(0)" ::: "memory");

        const float* chunkp = &sStage[w][buf][jc][0][0];
        floatx4 c0 = *(const floatx4*)(chunkp + o0);
        floatx4 c1 = *(const floatx4*)(chunkp + o1);
        floatx4 c2 = *(const floatx4*)(chunkp + o2);
        floatx4 c3 = *(const floatx4*)(chunkp + o3);
        short8 af0 = pack8(c0, c1);
        short8 af1 = pack8(c2, c3);
        if (it < 2) {
            // ds_reads of this buf must retire before the async overwrite can land
            asm volatile("s_waitcnt lgkmcnt(0)" ::: "memory");
            STAGE(it + 2, buf);
        }

        floatx4 accV[8], accS = (floatx4){0, 0, 0, 0};
        #pragma unroll
        for (int ct = 0; ct < 8; ++ct) accV[ct] = (floatx4){0, 0, 0, 0};
        __builtin_amdgcn_s_setprio(1);
        #pragma unroll
        for (int ct = 0; ct < 8; ++ct) {
            accV[ct] = __builtin_amdgcn_mfma_f32_16x16x32_bf16(af0, bfV[ct][0], accV[ct], 0, 0, 0);
            accV[ct] = __builtin_amdgcn_mfma_f32_16x16x32_bf16(af1, bfV[ct][1], accV[ct], 0, 0, 0);
        }
        accS = __builtin_amdgcn_mfma_f32_16x16x32_bf16(af0, bu0, accS, 0, 0, 0);
        accS = __builtin_amdgcn_mfma_f32_16x16x32_bf16(af1, bu1, accS, 0, 0, 0);
        __builtin_amdgcn_s_setprio(0);

        // scores -> per-wave LDS patch (same-wave write/read; program order holds)
        if (ncol < Hh) {
            #pragma unroll
            for (int r = 0; r < 4; ++r)
                sS[w][q8 * 4 + r][ncol] = (maskv != 0.f) ? accS[r] : -1e30f;
        }
        __builtin_amdgcn_wave_barrier();

        #pragma unroll
        for (int r = 0; r < 4; ++r) {
            floatx4 sc = *(const floatx4*)&sS[w][q8 * 4 + r][0];
            // scores are in log2 domain (log2e folded into u at prep): one v_exp_f32 each
            float e0 = __builtin_amdgcn_exp2f(sc[0]), e1 = __builtin_amdgcn_exp2f(sc[1]);
            float e2 = __builtin_amdgcn_exp2f(sc[2]), e3 = __builtin_amdgcn_exp2f(sc[3]);
            float inv = __builtin_amdgcn_rcpf((e0 + e1) + (e2 + e3));   // v_rcp_f32, ~1ulp
            float a0 = e0 * inv, a1 = e1 * inv, a2 = e2 * inv, a3 = e3 * inv;
            asumH += (ncol & 2) ? ((ncol & 1) ? a3 : a2) : ((ncol & 1) ? a1 : a0);
            float p;
            p = a0 * accV[0][r]; vs[0] += p; vm[0] = fmaxf(vm[0], p);
            p = a0 * accV[1][r]; vs[1] += p; vm[1] = fmaxf(vm[1], p);
            p = a1 * accV[2][r]; vs[2] += p; vm[2] = fmaxf(vm[2], p);
            p = a1 * accV[3][r]; vs[3] += p; vm[3] = fmaxf(vm[3], p);
            p = a2 * accV[4][r]; vs[4] += p; vm[4] = fmaxf(vm[4], p);
            p = a2 * accV[5][r]; vs[5] += p; vm[5] = fmaxf(vm[5], p);
            p = a3 * accV[6][r]; vs[6] += p; vm[6] = fmaxf(vm[6], p);
            p = a3 * accV[7][r]; vs[7] += p; vm[7] = fmaxf(vm[7], p);
        }
        __builtin_amdgcn_wave_barrier();   // sS reused next tile
    }
    #undef STAGE

    // q8-group reduction (once per wave)
    #pragma unroll
    for (int ct = 0; ct < 8; ++ct) {
        vs[ct] += __shfl_xor(vs[ct], 16, 64);
        vs[ct] += __shfl_xor(vs[ct], 32, 64);
        vm[ct] = fmaxf(vm[ct], __shfl_xor(vm[ct], 16, 64));
        vm[ct] = fmaxf(vm[ct], __shfl_xor(vm[ct], 32, 64));
    }
    asumH += __shfl_xor(asumH, 16, 64);
    asumH += __shfl_xor(asumH, 32, 64);

    if (lane < 16) {
        #pragma unroll
        for (int ct = 0; ct < 8; ++ct) {
            sVS[w][ct * 16 + lane] = vs[ct];
            sVM[w][ct * 16 + lane] = vm[ct];
        }
    }
    if (lane < Hh) sAS[w][lane] = asumH;   // lane = ncol = head
    __syncthreads();                       // all waves done -> sStage now dead, reusable
    if (tid < Hh) {
        sAsum[tid] = 1e-8f +
            (sAS[0][tid] + sAS[1][tid]) + (sAS[2][tid] + sAS[3][tid]);
    }
    __syncthreads();
    if (tid < OUTc) {
        float vsum = (sVS[0][tid] + sVS[1][tid]) + (sVS[2][tid] + sVS[3][tid]);
        float vmax = fmaxf(fmaxf(sVM[0][tid], sVM[1][tid]), fmaxf(sVM[2][tid], sVM[3][tid]));
        const int h = tid >> 5, d = tid & 31;
        sM[h * 65 + d]      = vsum / sAsum[h];
        sM[h * 65 + 33 + d] = vmax;
        if (tid < Hh) sM[tid * 65 + 32] = sAsum[tid];
    }
    __syncthreads();
    // fused W_R GEMV on transposed W_RT (coalesced: consecutive c = consecutive addr)
    {
        const int c = tid & 127, part = tid >> 7;
        const int j0 = part * 130;
        float a0 = 0.f, a1 = 0.f, a2 = 0.f, a3 = 0.f;
        #pragma unroll 4
        for (int j = j0; j < j0 + 128; j += 4) {
            a0 = fmaf(sM[j],     W_RT[(j)     * OUTc + c], a0);
            a1 = fmaf(sM[j + 1], W_RT[(j + 1) * OUTc + c], a1);
            a2 = fmaf(sM[j + 2], W_RT[(j + 2) * OUTc + c], a2);
            a3 = fmaf(sM[j + 3], W_RT[(j + 3) * OUTc + c], a3);
        }
        a0 = fmaf(sM[j0 + 128], W_RT[(j0 + 128) * OUTc + c], a0);
        a1 = fmaf(sM[j0 + 129], W_RT[(j0 + 129) * OUTc + c], a1);
        sAcc[part][c] = (a0 + a1) + (a2 + a3);
    }
    __syncthreads();
    if (tid < OUTc)
        out[bn * OUTc + tid] = sAcc[0][tid] + sAcc[1][tid];
}

extern "C" void kernel_launch(void* const* d_in, const int* in_sizes, int n_in,
                              void* d_out, int out_size, void* d_ws, size_t ws_size,
                              hipStream_t stream) {
    const float* h_x = (const float*)d_in[0];
    const float* h_e = (const float*)d_in[1];
    const float* h_m = (const float*)d_in[2];
    const float* W_Q = (const float*)d_in[3];
    const float* W_K = (const float*)d_in[4];
    const float* W_V = (const float*)d_in[5];
    const float* W_R = (const float*)d_in[6];
    float* out = (float*)d_out;

    float* ws            = (float*)d_ws;
    float* W_RT          = ws + WS_WRT;
    unsigned short* wfV  = (unsigned short*)(ws + WS_FRAGV);
    unsigned short* ufr  = (unsigned short*)(ws + WS_UFRAG);

    eama_prep<<<dim3(198), dim3(256), 0, stream>>>(W_Q, W_V, W_R, h_x, W_K, wfV, W_RT, ufr);
    eama_full<<<dim3(Bb * Nn), dim3(256), 0, stream>>>(h_e, h_m, wfV, ufr, W_RT, out);
}